// Round 2
// 578.424 us; speedup vs baseline: 1.0193x; 1.0193x over previous
//
#include <hip/hip_runtime.h>

// LogicGatedSNN: fully-fused single-kernel version (R2: compile fix).
//
// R1 theory: dur_us (589) >> sum of our kernel times (each < 162us, per the
// top-5 fill cutoff) -> ~330us of the timed region is harness arena
// poison/restore (1.07 GB fills @ ~164us). Our controllable part is ~260us
// vs a 768 MiB / 6.3 TB/s ~= 128us roofline.
//
// Fusion is legal per-row: trace update for row r needs only spike[r].
// One WAVE per row computes the binarized dot product (shfl_xor butterfly,
// every lane ends with the full sum -> no broadcast), then the same wave
// streams the trace RMW. No LDS, no barriers.
// Nontemporal hints on the single-use streams (syn read, trace read/write);
// x (32 KB) stays cached and is the only reused data.
//
// R2 fix: __builtin_nontemporal_load/store reject HIP_vector_type (struct);
// use clang native ext_vector_type(4) float instead.

#define IN_F 8192
#define OUT_F 8192
#define BLOCK 256
#define CHUNKS (IN_F / 4 / 64)   // 32 float4 iterations per lane per row

typedef float f32x4 __attribute__((ext_vector_type(4)));

__global__ __launch_bounds__(BLOCK) void snn_fused_kernel(
    const f32x4* __restrict__ x4,      // spike_input as float4 [IN_F/4]
    const float* __restrict__ syn,     // synapse_states [OUT_F, IN_F]
    const float* __restrict__ mem,     // membrane_potential [OUT_F]
    const float* __restrict__ thr,     // adaptive_threshold [OUT_F]
    const float* __restrict__ refr,    // refractory_period [OUT_F]
    const f32x4* __restrict__ tr4,     // eligibility_trace [OUT_F * IN_F/4]
    float* __restrict__ out_spikes,
    float* __restrict__ out_mem,
    float* __restrict__ out_refr,
    f32x4* __restrict__ otr4)          // out_trace [OUT_F * IN_F/4]
{
    const int wave = threadIdx.x >> 6;          // 0..3
    const int lane = threadIdx.x & 63;
    const int row  = (blockIdx.x << 2) + wave;

    const size_t base4 = (size_t)row * (IN_F / 4);
    const f32x4* __restrict__ syn4 = (const f32x4*)syn + base4;

    // Row scalars early (wave-uniform broadcast loads; latency hidden by
    // the syn stream below).
    const float r_in = refr[row];
    const float m_in = mem[row];
    const float t_in = thr[row];

    // ---- Phase 1: current = (syn > 50) . x  (pure read stream) ----
    float acc = 0.0f;
    #pragma unroll 8
    for (int it = 0; it < CHUNKS; ++it) {
        const int idx = (it << 6) + lane;
        const f32x4 s  = __builtin_nontemporal_load(&syn4[idx]);
        const f32x4 xv = x4[idx];                 // cached, 32 KB total
        acc += (s[0] > 50.0f) ? xv[0] : 0.0f;
        acc += (s[1] > 50.0f) ? xv[1] : 0.0f;
        acc += (s[2] > 50.0f) ? xv[2] : 0.0f;
        acc += (s[3] > 50.0f) ? xv[3] : 0.0f;
    }

    // 64-lane butterfly: every lane ends with the full row sum (exact:
    // operands are 0/1 counts, integer-valued in fp32).
    #pragma unroll
    for (int off = 32; off > 0; off >>= 1)
        acc += __shfl_xor(acc, off, 64);

    // ---- LIF scalars (all lanes compute identically; lane 0 writes) ----
    const float v     = m_in * 0.5f + acc * (1.0f - r_in * 0.5f);
    const float spike = (v >= t_in) ? 1.0f : 0.0f;
    if (lane == 0) {
        out_spikes[row] = spike;
        out_mem[row]    = v * (1.0f - spike);
        out_refr[row]   = fminf(fmaxf(r_in + spike - 0.1f, 0.0f), 1.0f);
    }

    // ---- Phase 2: trace = clip(trace*0.8 + spike*x, 0, 5)  (RMW stream) ----
    #pragma unroll 8
    for (int it = 0; it < CHUNKS; ++it) {
        const int idx = (it << 6) + lane;
        const f32x4 t  = __builtin_nontemporal_load(&tr4[base4 + idx]);
        const f32x4 xv = x4[idx];
        f32x4 o;
        o[0] = fminf(fmaxf(t[0] * 0.8f + spike * xv[0], 0.0f), 5.0f);
        o[1] = fminf(fmaxf(t[1] * 0.8f + spike * xv[1], 0.0f), 5.0f);
        o[2] = fminf(fmaxf(t[2] * 0.8f + spike * xv[2], 0.0f), 5.0f);
        o[3] = fminf(fmaxf(t[3] * 0.8f + spike * xv[3], 0.0f), 5.0f);
        __builtin_nontemporal_store(o, &otr4[base4 + idx]);
    }
}

extern "C" void kernel_launch(void* const* d_in, const int* in_sizes, int n_in,
                              void* d_out, int out_size, void* d_ws, size_t ws_size,
                              hipStream_t stream) {
    const float* x_in  = (const float*)d_in[0];  // spike_input
    const float* syn   = (const float*)d_in[1];  // synapse_states
    const float* mem   = (const float*)d_in[2];  // membrane_potential
    const float* thr   = (const float*)d_in[3];  // adaptive_threshold
    const float* trace = (const float*)d_in[4];  // eligibility_trace
    const float* refr  = (const float*)d_in[5];  // refractory_period

    float* out = (float*)d_out;
    float* out_spikes = out;                                     // [8192]
    float* out_mem    = out + OUT_F;                             // [8192]
    float* out_trace  = out + 2 * OUT_F;                         // [8192^2]
    float* out_refr   = out + 2 * OUT_F + (size_t)OUT_F * IN_F;  // [8192]

    snn_fused_kernel<<<OUT_F / 4, BLOCK, 0, stream>>>(
        (const f32x4*)x_in, syn, mem, thr, refr,
        (const f32x4*)trace,
        out_spikes, out_mem, out_refr,
        (f32x4*)out_trace);
}